// Round 1
// baseline (7560.072 us; speedup 1.0000x reference)
//
#include <hip/hip_runtime.h>
#include <cstdint>
#include <cstddef>

#define NBLK 256
#define NT   256
#define ROWS 32
#define DD   100
#define HH   110
#define NS   63

typedef __bf16 bf16x8 __attribute__((ext_vector_type(8)));
typedef float  f32x16 __attribute__((ext_vector_type(16)));

struct Params {
  const float* W; const float* yini; const float* zini;
  const float* g0; const float* b0; const float* g1; const float* b1;
  const float* g2; const float* b2; const float* g3; const float* b3;
  const float* w0; const float* w1; const float* w2;
  float* out; float* slots; int* cnts;
};

__device__ __forceinline__ float agent_ld(const float* p_) {
  return __hip_atomic_load(p_, __ATOMIC_RELAXED, __HIP_MEMORY_SCOPE_AGENT);
}

// one-shot grid barrier: arrive (release) then spin until all NBLK arrived.
__device__ __forceinline__ void barrier_arrive(int* cnt) {
  __threadfence();            // make this thread's atomics visible device-wide
  __syncthreads();            // all threads' fences done before rep arrives
  if (threadIdx.x == 0)
    __hip_atomic_fetch_add(cnt, 1, __ATOMIC_RELEASE, __HIP_MEMORY_SCOPE_AGENT);
}
__device__ __forceinline__ void barrier_wait(int* cnt) {
  if (threadIdx.x == 0) {
    while (__hip_atomic_load(cnt, __ATOMIC_ACQUIRE, __HIP_MEMORY_SCOPE_AGENT) < NBLK)
      __builtin_amdgcn_s_sleep(2);
  }
  __syncthreads();
}

// issue B-fragment global loads (w[k][n], masked to zero outside K x N)
template<int K, int N>
__device__ __forceinline__ void issueB(const float* wg, int n, int half, float (*t)[8]) {
#pragma unroll
  for (int c = 0; c < 7; ++c) {
#pragma unroll
    for (int j = 0; j < 8; ++j) {
      int k = c * 16 + half * 8 + j;
      t[c][j] = (k < K && n < N) ? wg[k * N + n] : 0.f;
    }
  }
}

__device__ __forceinline__ f32x16 run_mfma(const __bf16* hs, const float (*t)[8],
                                           int col, int half) {
  f32x16 acc = {0.f,0.f,0.f,0.f,0.f,0.f,0.f,0.f,0.f,0.f,0.f,0.f,0.f,0.f,0.f,0.f};
#pragma unroll
  for (int c = 0; c < 7; ++c) {
    bf16x8 bfv;
#pragma unroll
    for (int j = 0; j < 8; ++j) bfv[j] = (__bf16)t[c][j];
    bf16x8 af = *(const bf16x8*)(hs + col * 120 + c * 16 + half * 8);
    acc = __builtin_amdgcn_mfma_f32_32x32x16_bf16(af, bfv, acc, 0, 0, 0);
  }
  return acc;
}

// column (per-output-feature) partial stats over this block's 32 rows, from frags
__device__ __forceinline__ void frag_stats(const f32x16& acc, float* slot,
                                           int n, int N, int half) {
  float sm = 0.f, sq = 0.f;
#pragma unroll
  for (int i = 0; i < 16; ++i) { float v = acc[i]; sm += v; sq += v * v; }
  sm += __shfl_xor(sm, 32);
  sq += __shfl_xor(sq, 32);
  if (half == 0 && n < N) {
    atomicAdd(&slot[n], sm);
    atomicAdd(&slot[128 + n], sq);
  }
}

// BN affine params for this lane's column (a*x + c), optional extra scale
__device__ __forceinline__ void bn_ac(const float* slot, const float* gam,
                                      const float* bet, int n, int N, float scale,
                                      float& a, float& c) {
  a = 0.f; c = 0.f;
  if (n < N) {
    float sm = agent_ld(&slot[n]);
    float sq = agent_ld(&slot[128 + n]);
    float mean = sm * (1.f / 8192.f);
    float var  = fmaxf(sq * (1.f / 8192.f) - mean * mean, 0.f);
    float au = gam[n] * rsqrtf(var + 1e-6f);
    a = au * scale;
    c = (bet[n] - mean * au) * scale;
  }
}

__device__ __forceinline__ void write_h(__bf16* hs, const f32x16& acc,
                                        float a, float c, int n, int half) {
  if (n < 112) {
#pragma unroll
    for (int i = 0; i < 16; ++i) {
      int row = (i & 3) + 8 * (i >> 2) + 4 * half;
      float v = fmaxf(acc[i] * a + c, 0.f);   // relu; n>=N -> a=c=0 -> writes pad zeros
      hs[row * 120 + n] = (__bf16)v;
    }
  }
}

__device__ __forceinline__ void write_z(float* zs, const f32x16& acc,
                                        float a, float c, int n, int half) {
  if (n < DD) {
#pragma unroll
    for (int i = 0; i < 16; ++i) {
      int row = (i & 3) + 8 * (i >> 2) + 4 * half;
      zs[row * 104 + n] = acc[i] * a + c;
    }
  }
}

__global__ __launch_bounds__(NT) void bsde_kernel(Params p) {
  __shared__ float xs[ROWS * 104];
  __shared__ float zs[ROWS * 104];
  __shared__ float dws[ROWS * 104];
  __shared__ float ys[ROWS];
  __shared__ __bf16 hsb[ROWS * 120];
  __shared__ float aS[128], cS[128];

  const int tid  = threadIdx.x;
  const int lane = tid & 63;
  const int wv   = tid >> 6;
  const int col  = lane & 31;
  const int half = lane >> 5;
  const int n    = wv * 32 + col;
  const int b0   = blockIdx.x * ROWS;

  // ---- init persistent state ----
  {
    float z0 = p.zini[0];
    for (int i = tid; i < ROWS * 104; i += NT) { xs[i] = 1.57079632679f; zs[i] = z0; }
    if (tid < ROWS) ys[tid] = p.yini[0];
  }
  // stage dW for step 0
  for (int idx = tid; idx < ROWS * 128; idx += NT) {
    int r = idx >> 7, d = idx & 127;
    if (d < DD) {
      const float* wr = p.W + (size_t)(b0 + r) * 6400 + d;
      dws[r * 104 + d] = wr[100] - wr[0];
    }
  }
  __syncthreads();

  for (int s = 0; s < NS; ++s) {
    float* slot = p.slots + (size_t)s * 1024;
    int*   cn   = p.cnts + s * 4;

    // ---- phase 0: x,y update (block-local) ----
    {
      int r = tid >> 3, l8 = tid & 7;
      float yr = ys[r];
      float ssum = 0.f, zdw = 0.f;
#pragma unroll
      for (int i = 0; i < 13; ++i) {
        int d = l8 + 8 * i;
        if (d < DD) {
          float dw = dws[r * 104 + d];
          float xv = xs[r * 104 + d] + 0.3f * dw * yr;
          xs[r * 104 + d] = xv;
          ssum += __sinf(xv);
          zdw  += zs[r * 104 + d] * dw;
        }
      }
      ssum += __shfl_down(ssum, 4, 8);
      ssum += __shfl_down(ssum, 2, 8);
      ssum += __shfl_down(ssum, 1, 8);
      zdw  += __shfl_down(zdw, 4, 8);
      zdw  += __shfl_down(zdw, 2, 8);
      zdw  += __shfl_down(zdw, 1, 8);
      if (l8 == 0) {
        float ec = __expf(-0.3f * (1.f - (float)s * (1.f / 64.f)));
        float tc = 0.1f * ssum;
        float drift = -0.1f * yr + 0.045f * ec * tc * tc * tc;
        ys[r] = yr - drift * (1.f / 64.f) + zdw;
      }
    }
    __syncthreads();

    // ---- BN0 stats (h = [x | y], 101 features) ----
    if (tid < 101) {
      float sm = 0.f, sq = 0.f;
      if (tid < DD) {
        for (int r = 0; r < ROWS; ++r) { float v = xs[r * 104 + tid]; sm += v; sq += v * v; }
      } else {
        for (int r = 0; r < ROWS; ++r) { float v = ys[r]; sm += v; sq += v * v; }
      }
      atomicAdd(&slot[tid], sm);
      atomicAdd(&slot[128 + tid], sq);
    }
    barrier_arrive(cn);
    float tB[7][8];
    issueB<101, HH>(p.w0 + (size_t)s * 11110, n, half, tB);   // overlap w/ barrier
    barrier_wait(cn);
    if (tid < 128) {
      float a = 0.f, c = 0.f;
      if (tid < 101) {
        float sm = agent_ld(&slot[tid]);
        float sq = agent_ld(&slot[128 + tid]);
        float mean = sm * (1.f / 8192.f);
        float var  = fmaxf(sq * (1.f / 8192.f) - mean * mean, 0.f);
        float au = p.g0[s * 101 + tid] * rsqrtf(var + 1e-6f);
        a = au; c = p.b0[s * 101 + tid] - mean * au;
      }
      aS[tid] = a; cS[tid] = c;
    }
    __syncthreads();
    // build normalized bf16 h (cols 101..111 zero pad)
    for (int idx = tid; idx < ROWS * 128; idx += NT) {
      int r = idx >> 7, d = idx & 127;
      if (d < 112) {
        float v = (d < DD)  ? xs[r * 104 + d] * aS[d] + cS[d]
                : (d == DD) ? ys[r] * aS[DD] + cS[DD] : 0.f;
        hsb[r * 120 + d] = (__bf16)v;
      }
    }
    __syncthreads();

    // ---- L0: h @ w0 -> BN1 -> relu ----
    {
      f32x16 acc = run_mfma(hsb, tB, col, half);
      float* sl = slot + 256;
      frag_stats(acc, sl, n, HH, half);
      barrier_arrive(cn + 1);
      issueB<HH, HH>(p.w1 + (size_t)s * 12100, n, half, tB);
      barrier_wait(cn + 1);
      float a, c;
      bn_ac(sl, p.g1 + s * HH, p.b1 + s * HH, n, HH, 1.f, a, c);
      write_h(hsb, acc, a, c, n, half);
      __syncthreads();
    }
    // ---- L1: h @ w1 -> BN2 -> relu ----
    {
      f32x16 acc = run_mfma(hsb, tB, col, half);
      float* sl = slot + 512;
      frag_stats(acc, sl, n, HH, half);
      barrier_arrive(cn + 2);
      issueB<HH, DD>(p.w2 + (size_t)s * 11000, n, half, tB);
      barrier_wait(cn + 2);
      float a, c;
      bn_ac(sl, p.g2 + s * HH, p.b2 + s * HH, n, HH, 1.f, a, c);
      write_h(hsb, acc, a, c, n, half);
      __syncthreads();
    }
    // ---- L2: h @ w2 -> BN3 -> z/100  (bias2 is batch-constant: cancels in BN) ----
    {
      f32x16 acc = run_mfma(hsb, tB, col, half);
      float* sl = slot + 768;
      frag_stats(acc, sl, n, DD, half);
      barrier_arrive(cn + 3);
      // prefetch next step's dW under the barrier (keep step-62 dW for final update)
      if (s + 1 < NS) {
        for (int idx = tid; idx < ROWS * 128; idx += NT) {
          int r = idx >> 7, d = idx & 127;
          if (d < DD) {
            const float* wr = p.W + (size_t)(b0 + r) * 6400 + (s + 1) * 100 + d;
            dws[r * 104 + d] = wr[100] - wr[0];
          }
        }
      }
      barrier_wait(cn + 3);
      float a, c;
      bn_ac(sl, p.g3 + s * DD, p.b3 + s * DD, n, DD, 0.01f, a, c);
      write_z(zs, acc, a, c, n, half);
      __syncthreads();
    }
  }

  // ---- final extra update with dW[-1] (reference's trailing step) ----
  {
    int r = tid >> 3, l8 = tid & 7;
    float yr = ys[r];
    float ssum = 0.f, zdw = 0.f;
#pragma unroll
    for (int i = 0; i < 13; ++i) {
      int d = l8 + 8 * i;
      if (d < DD) {
        float dw = dws[r * 104 + d];
        float xv = xs[r * 104 + d] + 0.3f * dw * yr;
        xs[r * 104 + d] = xv;
        ssum += __sinf(xv);
        zdw  += zs[r * 104 + d] * dw;
      }
    }
    ssum += __shfl_down(ssum, 4, 8);
    ssum += __shfl_down(ssum, 2, 8);
    ssum += __shfl_down(ssum, 1, 8);
    zdw  += __shfl_down(zdw, 4, 8);
    zdw  += __shfl_down(zdw, 2, 8);
    zdw  += __shfl_down(zdw, 1, 8);
    if (l8 == 0) {
      float ec = __expf(-0.3f * (1.f - 62.f * (1.f / 64.f)));
      float tc = 0.1f * ssum;
      float drift = -0.1f * yr + 0.045f * ec * tc * tc * tc;
      ys[r] = yr - drift * (1.f / 64.f) + zdw;
    }
  }
  __syncthreads();

  // ---- write outputs: x [8192,100] then y [8192,1] ----
  for (int idx = tid; idx < ROWS * 128; idx += NT) {
    int r = idx >> 7, d = idx & 127;
    if (d < DD) p.out[(size_t)(b0 + r) * 100 + d] = xs[r * 104 + d];
  }
  if (tid < ROWS) p.out[819200 + b0 + tid] = ys[tid];
}

extern "C" void kernel_launch(void* const* d_in, const int* in_sizes, int n_in,
                              void* d_out, int out_size, void* d_ws, size_t ws_size,
                              hipStream_t stream) {
  Params p;
  p.W    = (const float*)d_in[0];
  p.yini = (const float*)d_in[1];
  p.zini = (const float*)d_in[2];
  p.g0   = (const float*)d_in[3];  p.b0 = (const float*)d_in[4];
  p.g1   = (const float*)d_in[5];  p.b1 = (const float*)d_in[6];
  p.g2   = (const float*)d_in[7];  p.b2 = (const float*)d_in[8];
  p.g3   = (const float*)d_in[9];  p.b3 = (const float*)d_in[10];
  p.w0   = (const float*)d_in[11]; p.w1 = (const float*)d_in[12];
  p.w2   = (const float*)d_in[13];
  // d_in[14] = bias2 (all zeros; batch-constant -> cancels inside BN3)
  p.out   = (float*)d_out;
  p.slots = (float*)d_ws;                              // 63*4 slots x 256 floats
  p.cnts  = (int*)((char*)d_ws + (size_t)NS * 4 * 256 * 4);

  size_t zbytes = (size_t)NS * 4 * 256 * 4 + (size_t)NS * 4 * 4;  // slots + counters
  hipMemsetAsync(d_ws, 0, zbytes, stream);
  bsde_kernel<<<dim3(NBLK), dim3(NT), 0, stream>>>(p);
}

// Round 2
// 4186.269 us; speedup vs baseline: 1.8059x; 1.8059x over previous
//
#include <hip/hip_runtime.h>
#include <cstdint>
#include <cstddef>

#define NBLK 128
#define NT   256
#define ROWS 64
#define DD   100
#define HH   110
#define NS   63
#define NGRP 16
#define GRP  (NBLK / NGRP)

typedef __bf16 bf16x8 __attribute__((ext_vector_type(8)));
typedef float  f32x16 __attribute__((ext_vector_type(16)));

struct Params {
  const float* W; const float* yini; const float* zini;
  const float* g0; const float* b0; const float* g1; const float* b1;
  const float* g2; const float* b2; const float* g3; const float* b3;
  const float* w0; const float* w1; const float* w2;
  float* out; float* slots; int* cnts;
};

// relaxed agent-scope load: global_load with L1/L2-bypass encoding, NO buffer_inv
__device__ __forceinline__ float agent_ld(const float* p_) {
  return __hip_atomic_load(p_, __ATOMIC_RELAXED, __HIP_MEMORY_SCOPE_AGENT);
}

// Cache-op-free grid barrier. Stats atomics (device scope) execute at the MALL;
// s_waitcnt vmcnt(0) guarantees they are acked there before the flag add, so any
// observer of the flag (via L2-bypassing relaxed atomic load) sees final stats.
// No release/acquire -> no buffer_wbl2 / buffer_inv cache maintenance.
__device__ __forceinline__ void sync_arrive(int* cn) {
  asm volatile("s_waitcnt vmcnt(0)" ::: "memory");
  __syncthreads();
  if (threadIdx.x == 0)
    __hip_atomic_fetch_add(&cn[(blockIdx.x & (NGRP - 1)) * 16], 1,
                           __ATOMIC_RELAXED, __HIP_MEMORY_SCOPE_AGENT);
}
__device__ __forceinline__ void sync_wait(int* cn) {
  if (threadIdx.x < NGRP) {
    while (__hip_atomic_load(&cn[threadIdx.x * 16], __ATOMIC_RELAXED,
                             __HIP_MEMORY_SCOPE_AGENT) < GRP)
      __builtin_amdgcn_s_sleep(1);
  }
  __syncthreads();
  asm volatile("" ::: "memory");
}

// issue B-fragment global loads (w[k][n], masked to zero outside K x N)
template<int K, int N>
__device__ __forceinline__ void issueB(const float* wg, int n, int half, float (*t)[8]) {
#pragma unroll
  for (int c = 0; c < 7; ++c) {
#pragma unroll
    for (int j = 0; j < 8; ++j) {
      int k = c * 16 + half * 8 + j;
      t[c][j] = (k < K && n < N) ? wg[k * N + n] : 0.f;
    }
  }
}

// two 32-row tiles (M=64) sharing the B fragments
__device__ __forceinline__ void run_mfma2(const __bf16* hs, const float (*t)[8],
                                          int col, int half, f32x16* acc) {
  acc[0] = (f32x16)(0.f);
  acc[1] = (f32x16)(0.f);
#pragma unroll
  for (int c = 0; c < 7; ++c) {
    bf16x8 bfv;
#pragma unroll
    for (int j = 0; j < 8; ++j) bfv[j] = (__bf16)t[c][j];
    bf16x8 a0 = *(const bf16x8*)(hs + col * 120 + c * 16 + half * 8);
    bf16x8 a1 = *(const bf16x8*)(hs + (32 + col) * 120 + c * 16 + half * 8);
    acc[0] = __builtin_amdgcn_mfma_f32_32x32x16_bf16(a0, bfv, acc[0], 0, 0, 0);
    acc[1] = __builtin_amdgcn_mfma_f32_32x32x16_bf16(a1, bfv, acc[1], 0, 0, 0);
  }
}

// per-feature partial stats over this block's 64 rows
__device__ __forceinline__ void frag_stats(const f32x16* acc, float* slot,
                                           int n, int N, int half) {
  float sm = 0.f, sq = 0.f;
#pragma unroll
  for (int m = 0; m < 2; ++m)
#pragma unroll
    for (int i = 0; i < 16; ++i) { float v = acc[m][i]; sm += v; sq += v * v; }
  sm += __shfl_xor(sm, 32);
  sq += __shfl_xor(sq, 32);
  if (half == 0 && n < N) {
    atomicAdd(&slot[n], sm);
    atomicAdd(&slot[128 + n], sq);
  }
}

__device__ __forceinline__ void bn_ac(const float* slot, const float* gam,
                                      const float* bet, int n, int N, float scale,
                                      float& a, float& c) {
  a = 0.f; c = 0.f;
  if (n < N) {
    float sm = agent_ld(&slot[n]);
    float sq = agent_ld(&slot[128 + n]);
    float mean = sm * (1.f / 8192.f);
    float var  = fmaxf(sq * (1.f / 8192.f) - mean * mean, 0.f);
    float au = gam[n] * rsqrtf(var + 1e-6f);
    a = au * scale;
    c = (bet[n] - mean * au) * scale;
  }
}

__device__ __forceinline__ void write_h(__bf16* hs, const f32x16* acc,
                                        float a, float c, int n, int half) {
  if (n < 112) {
#pragma unroll
    for (int m = 0; m < 2; ++m)
#pragma unroll
      for (int i = 0; i < 16; ++i) {
        int row = m * 32 + (i & 3) + 8 * (i >> 2) + 4 * half;
        float v = fmaxf(acc[m][i] * a + c, 0.f);
        hs[row * 120 + n] = (__bf16)v;
      }
  }
}

__device__ __forceinline__ void write_z(float* zs, const f32x16* acc,
                                        float a, float c, int n, int half) {
  if (n < DD) {
#pragma unroll
    for (int m = 0; m < 2; ++m)
#pragma unroll
      for (int i = 0; i < 16; ++i) {
        int row = m * 32 + (i & 3) + 8 * (i >> 2) + 4 * half;
        zs[row * 104 + n] = acc[m][i] * a + c;
      }
  }
}

__global__ __launch_bounds__(NT) void bsde_kernel(Params p) {
  __shared__ float xs[ROWS * 104];
  __shared__ float zs[ROWS * 104];
  __shared__ float dws[ROWS * 104];
  __shared__ float ys[ROWS];
  __shared__ __bf16 hsb[ROWS * 120];
  __shared__ float aS[128], cS[128];

  const int tid  = threadIdx.x;
  const int lane = tid & 63;
  const int wv   = tid >> 6;
  const int col  = lane & 31;
  const int half = lane >> 5;
  const int n    = wv * 32 + col;
  const int b0   = blockIdx.x * ROWS;

  // ---- init persistent state ----
  {
    float z0 = p.zini[0];
    for (int i = tid; i < ROWS * 104; i += NT) { xs[i] = 1.57079632679f; zs[i] = z0; }
    if (tid < ROWS) ys[tid] = p.yini[0];
  }
  for (int idx = tid; idx < ROWS * 128; idx += NT) {
    int r = idx >> 7, d = idx & 127;
    if (d < DD) {
      const float* wr = p.W + (size_t)(b0 + r) * 6400 + d;
      dws[r * 104 + d] = wr[100] - wr[0];
    }
  }
  __syncthreads();

  for (int s = 0; s < NS; ++s) {
    float* slot = p.slots + (size_t)s * 1024;
    int*   cn0  = p.cnts + (size_t)(s * 4) * (NGRP * 16);

    // ---- phase 0: x,y update (block-local) ----
    {
      int r = tid >> 2, l4 = tid & 3;
      float yr = ys[r];
      float ssum = 0.f, zdw = 0.f;
#pragma unroll
      for (int i = 0; i < 25; ++i) {
        int d = l4 + 4 * i;
        float dw = dws[r * 104 + d];
        float xv = xs[r * 104 + d] + 0.3f * dw * yr;
        xs[r * 104 + d] = xv;
        ssum += __sinf(xv);
        zdw  += zs[r * 104 + d] * dw;
      }
      ssum += __shfl_down(ssum, 2, 4);
      ssum += __shfl_down(ssum, 1, 4);
      zdw  += __shfl_down(zdw, 2, 4);
      zdw  += __shfl_down(zdw, 1, 4);
      if (l4 == 0) {
        float ec = __expf(-0.3f * (1.f - (float)s * (1.f / 64.f)));
        float tc = 0.1f * ssum;
        float drift = -0.1f * yr + 0.045f * ec * tc * tc * tc;
        ys[r] = yr - drift * (1.f / 64.f) + zdw;
      }
    }
    __syncthreads();

    // ---- BN0 stats (h = [x | y], 101 features) ----
    if (tid < 101) {
      float sm = 0.f, sq = 0.f;
      if (tid < DD) {
        for (int r = 0; r < ROWS; ++r) { float v = xs[r * 104 + tid]; sm += v; sq += v * v; }
      } else {
        for (int r = 0; r < ROWS; ++r) { float v = ys[r]; sm += v; sq += v * v; }
      }
      atomicAdd(&slot[tid], sm);
      atomicAdd(&slot[128 + tid], sq);
    }
    sync_arrive(cn0);
    float tB[7][8];
    issueB<101, HH>(p.w0 + (size_t)s * 11110, n, half, tB);   // overlap w/ barrier
    sync_wait(cn0);
    if (tid < 128) {
      float a = 0.f, c = 0.f;
      if (tid < 101) {
        float sm = agent_ld(&slot[tid]);
        float sq = agent_ld(&slot[128 + tid]);
        float mean = sm * (1.f / 8192.f);
        float var  = fmaxf(sq * (1.f / 8192.f) - mean * mean, 0.f);
        float au = p.g0[s * 101 + tid] * rsqrtf(var + 1e-6f);
        a = au; c = p.b0[s * 101 + tid] - mean * au;
      }
      aS[tid] = a; cS[tid] = c;
    }
    __syncthreads();
    for (int idx = tid; idx < ROWS * 128; idx += NT) {
      int r = idx >> 7, d = idx & 127;
      if (d < 112) {
        float v = (d < DD)  ? xs[r * 104 + d] * aS[d] + cS[d]
                : (d == DD) ? ys[r] * aS[DD] + cS[DD] : 0.f;
        hsb[r * 120 + d] = (__bf16)v;
      }
    }
    __syncthreads();

    f32x16 acc[2];
    // ---- L0: h @ w0 -> BN1 -> relu ----
    {
      run_mfma2(hsb, tB, col, half, acc);
      float* sl = slot + 256;
      frag_stats(acc, sl, n, HH, half);
      int* cn = cn0 + NGRP * 16;
      sync_arrive(cn);
      issueB<HH, HH>(p.w1 + (size_t)s * 12100, n, half, tB);
      sync_wait(cn);
      float a, c;
      bn_ac(sl, p.g1 + s * HH, p.b1 + s * HH, n, HH, 1.f, a, c);
      write_h(hsb, acc, a, c, n, half);
      __syncthreads();
    }
    // ---- L1: h @ w1 -> BN2 -> relu ----
    {
      run_mfma2(hsb, tB, col, half, acc);
      float* sl = slot + 512;
      frag_stats(acc, sl, n, HH, half);
      int* cn = cn0 + 2 * NGRP * 16;
      sync_arrive(cn);
      issueB<HH, DD>(p.w2 + (size_t)s * 11000, n, half, tB);
      sync_wait(cn);
      float a, c;
      bn_ac(sl, p.g2 + s * HH, p.b2 + s * HH, n, HH, 1.f, a, c);
      write_h(hsb, acc, a, c, n, half);
      __syncthreads();
    }
    // ---- L2: h @ w2 -> BN3 -> z/100  (bias2 zero & batch-constant: cancels in BN) ----
    {
      run_mfma2(hsb, tB, col, half, acc);
      float* sl = slot + 768;
      frag_stats(acc, sl, n, DD, half);
      int* cn = cn0 + 3 * NGRP * 16;
      sync_arrive(cn);
      if (s + 1 < NS) {   // prefetch next step's dW under the barrier
        for (int idx = tid; idx < ROWS * 128; idx += NT) {
          int r = idx >> 7, d = idx & 127;
          if (d < DD) {
            const float* wr = p.W + (size_t)(b0 + r) * 6400 + (s + 1) * 100 + d;
            dws[r * 104 + d] = wr[100] - wr[0];
          }
        }
      }
      sync_wait(cn);
      float a, c;
      bn_ac(sl, p.g3 + s * DD, p.b3 + s * DD, n, DD, 0.01f, a, c);
      write_z(zs, acc, a, c, n, half);
      __syncthreads();
    }
  }

  // ---- final extra update with dW[-1] ----
  {
    int r = tid >> 2, l4 = tid & 3;
    float yr = ys[r];
    float ssum = 0.f, zdw = 0.f;
#pragma unroll
    for (int i = 0; i < 25; ++i) {
      int d = l4 + 4 * i;
      float dw = dws[r * 104 + d];
      float xv = xs[r * 104 + d] + 0.3f * dw * yr;
      xs[r * 104 + d] = xv;
      ssum += __sinf(xv);
      zdw  += zs[r * 104 + d] * dw;
    }
    ssum += __shfl_down(ssum, 2, 4);
    ssum += __shfl_down(ssum, 1, 4);
    zdw  += __shfl_down(zdw, 2, 4);
    zdw  += __shfl_down(zdw, 1, 4);
    if (l4 == 0) {
      float ec = __expf(-0.3f * (1.f - 62.f * (1.f / 64.f)));
      float tc = 0.1f * ssum;
      float drift = -0.1f * yr + 0.045f * ec * tc * tc * tc;
      ys[r] = yr - drift * (1.f / 64.f) + zdw;
    }
  }
  __syncthreads();

  // ---- outputs: x [8192,100] then y [8192,1] ----
  for (int idx = tid; idx < ROWS * 128; idx += NT) {
    int r = idx >> 7, d = idx & 127;
    if (d < DD) p.out[(size_t)(b0 + r) * 100 + d] = xs[r * 104 + d];
  }
  if (tid < ROWS) p.out[819200 + b0 + tid] = ys[tid];
}

extern "C" void kernel_launch(void* const* d_in, const int* in_sizes, int n_in,
                              void* d_out, int out_size, void* d_ws, size_t ws_size,
                              hipStream_t stream) {
  Params p;
  p.W    = (const float*)d_in[0];
  p.yini = (const float*)d_in[1];
  p.zini = (const float*)d_in[2];
  p.g0   = (const float*)d_in[3];  p.b0 = (const float*)d_in[4];
  p.g1   = (const float*)d_in[5];  p.b1 = (const float*)d_in[6];
  p.g2   = (const float*)d_in[7];  p.b2 = (const float*)d_in[8];
  p.g3   = (const float*)d_in[9];  p.b3 = (const float*)d_in[10];
  p.w0   = (const float*)d_in[11]; p.w1 = (const float*)d_in[12];
  p.w2   = (const float*)d_in[13];
  p.out   = (float*)d_out;
  p.slots = (float*)d_ws;
  p.cnts  = (int*)((char*)d_ws + (size_t)NS * 4 * 256 * 4);

  size_t zbytes = (size_t)NS * 4 * 256 * 4            // stats slots
                + (size_t)NS * 4 * NGRP * 16 * 4;     // group counters
  hipMemsetAsync(d_ws, 0, zbytes, stream);
  bsde_kernel<<<dim3(NBLK), dim3(NT), 0, stream>>>(p);
}